// Round 1
// baseline (1916.416 us; speedup 1.0000x reference)
//
#include <hip/hip_runtime.h>
#include <hip/hip_bf16.h>
#include <cstdint>
#include <cstddef>

// Problem dims (fixed by the reference)
#define BB 16384
#define DD 1024
#define SS 2048

typedef __attribute__((ext_vector_type(8))) short s8vec;   // 8 bf16 payload
typedef __attribute__((ext_vector_type(4))) short s4vec;
typedef __attribute__((ext_vector_type(4))) float f4vec;

static __device__ __forceinline__ short f2bf(float x) {
  __hip_bfloat16 h = __float2bfloat16(x);
  union { __hip_bfloat16 b; short s; } u; u.b = h; return u.s;
}

static __device__ __forceinline__ float softplus_f(float x) {
  return (x > 20.f) ? x : log1pf(expf(x));
}

// async global->LDS, 16B per lane. LDS dest must be wave-uniform base + lane*16.
static __device__ __forceinline__ void gload16(const void* g, void* l) {
  __builtin_amdgcn_global_load_lds((__attribute__((address_space(1))) void*)g,
                                   (__attribute__((address_space(3))) void*)l,
                                   16, 0, 0);
}

struct EpiParams {
  float* out;          // A1 (EPI 0/1) or h (EPI 3)
  const float* bias;   // b_step / b_in / b_out
  const float* step;   // A1 (EPI 2)
  const float* state;  // fp32 state (EPI 2)
  const float* carry;  // carry_scale (EPI 2)
  const float* ldec;   // log_decay (EPI 2)
  float* out_state;    // d_out + B*D (EPI 2)
  short* xy;           // XY bf16 buffer (EPI 2)
  const float* x;      // x_t fp32 (EPI 3 residual)
};

// C = A(M,K) @ Bt(N,K)^T ; 128x128 tile, BK=32, 256 threads (4 waves, 2x2),
// each wave 64x64 via 4x4 grid of 16x16x32 bf16 MFMA.
template<int EPI>
__global__ __launch_bounds__(256)
void gemm_bt(const short* __restrict__ A, int lda,
             const short* __restrict__ Bt, int ldb,
             int K, EpiParams ep)
{
  __shared__ short Alds[128 * 32];
  __shared__ short Blds[128 * 32];

  const int tid  = threadIdx.x;
  const int lane = tid & 63;
  const int wv   = tid >> 6;
  const int bm   = blockIdx.y;
  const int bn   = blockIdx.x;

  // staging: each wave stages 32 rows of A-tile and 32 rows of Bt-tile,
  // in 2 chunks of 16 rows; lane covers (row = lane>>2, col8 = (lane&3)*8)
  const int srow = wv * 32 + (lane >> 2);
  const int scol = (lane & 3) * 8;
  const short* Ag = A  + (size_t)(bm * 128 + srow) * lda + scol;
  const short* Bg = Bt + (size_t)(bn * 128 + srow) * ldb + scol;
  short* Al = &Alds[(wv * 32) * 32] + lane * 8;
  short* Bl = &Blds[(wv * 32) * 32] + lane * 8;

  const int wM = (wv >> 1) * 64;
  const int wN = (wv & 1) * 64;
  const int frow = lane & 15;
  const int fk   = (lane >> 4) * 8;

  f4vec acc[4][4];
#pragma unroll
  for (int i = 0; i < 4; i++)
#pragma unroll
    for (int j = 0; j < 4; j++) acc[i][j] = (f4vec){0.f, 0.f, 0.f, 0.f};

  for (int k0 = 0; k0 < K; k0 += 32) {
    __syncthreads();  // previous tile fully consumed
    gload16(Ag + k0,            Al);
    gload16(Ag + k0 + 16 * lda, Al + 16 * 32);
    gload16(Bg + k0,            Bl);
    gload16(Bg + k0 + 16 * ldb, Bl + 16 * 32);
    __syncthreads();  // compiler inserts vmcnt(0) drain before s_barrier

    s8vec a[4], b[4];
#pragma unroll
    for (int i = 0; i < 4; i++)
      a[i] = *(const s8vec*)&Alds[(wM + i * 16 + frow) * 32 + fk];
#pragma unroll
    for (int j = 0; j < 4; j++)
      b[j] = *(const s8vec*)&Blds[(wN + j * 16 + frow) * 32 + fk];

#pragma unroll
    for (int i = 0; i < 4; i++)
#pragma unroll
      for (int j = 0; j < 4; j++)
        acc[i][j] = __builtin_amdgcn_mfma_f32_16x16x32_bf16(a[i], b[j], acc[i][j], 0, 0, 0);
  }

  // C/D layout: col = lane&15, row = (lane>>4)*4 + reg  (m89-verified)
  const int erow = bm * 128 + wM + (lane >> 4) * 4;
  const int ecol = bn * 128 + wN + (lane & 15);

#pragma unroll
  for (int i = 0; i < 4; i++) {
#pragma unroll
    for (int j = 0; j < 4; j++) {
      const int col = ecol + j * 16;
#pragma unroll
      for (int r = 0; r < 4; r++) {
        const int row = erow + i * 16 + r;
        const float v = acc[i][j][r];
        if constexpr (EPI == 0) {            // A1 = softplus(acc + b_step)
          ep.out[(size_t)row * SS + col] = softplus_f(v + ep.bias[col]);
        } else if constexpr (EPI == 1) {     // A1 += 0.1*softplus(acc)
          const size_t idx = (size_t)row * SS + col;
          ep.out[idx] = ep.out[idx] + 0.1f * softplus_f(v);
        } else if constexpr (EPI == 2) {     // fused state update
          const size_t idx = (size_t)row * SS + col;
          const float step = ep.step[idx];
          const float dec  = expf(-step * expf(ep.ldec[col])) * ep.carry[idx];
          const float prop = tanhf(v + ep.bias[col]);
          const float ns   = dec * ep.state[idx] + (1.f - dec) * prop;
          ep.out_state[idx] = ns;
          ep.xy[(size_t)row * 3072 + 1024 + col] = f2bf(ns);
        } else {                             // h = acc + b_out + x
          const size_t idx = (size_t)row * DD + col;
          ep.out[idx] = v + ep.bias[col] + ep.x[idx];
        }
      }
    }
  }
}

// transpose-cast: src fp32 (R,C) -> dst bf16 block at rows [0,C), cols [co, co+R) of ldd-wide buffer
__global__ __launch_bounds__(256)
void tcast(const float* __restrict__ src, int R, int C,
           short* __restrict__ dst, int ldd, int co)
{
  __shared__ float tile[32][33];
  const int c0 = blockIdx.x * 32;
  const int r0 = blockIdx.y * 32;
  const int tx = threadIdx.x;  // 0..31
  const int ty = threadIdx.y;  // 0..7
#pragma unroll
  for (int i = 0; i < 4; i++)
    tile[ty * 4 + i][tx] = src[(size_t)(r0 + ty * 4 + i) * C + c0 + tx];
  __syncthreads();
#pragma unroll
  for (int i = 0; i < 4; i++)
    dst[(size_t)(c0 + ty * 4 + i) * ldd + co + r0 + tx] = f2bf(tile[tx][ty * 4 + i]);
}

__global__ __launch_bounds__(256)
void cast_xc(const float4* __restrict__ x, const float4* __restrict__ c,
             short* __restrict__ Xcat, short* __restrict__ XY)
{
  const size_t i = (size_t)blockIdx.x * 256 + threadIdx.x;
  if (i >= (size_t)BB * (DD / 4)) return;
  const size_t row = i >> 8;           // DD/4 = 256
  const int col4 = (int)(i & 255);
  const float4 xv = x[i];
  const float4 cv = c[i];
  const s4vec xs = { f2bf(xv.x), f2bf(xv.y), f2bf(xv.z), f2bf(xv.w) };
  const s4vec cs = { f2bf(cv.x), f2bf(cv.y), f2bf(cv.z), f2bf(cv.w) };
  *(s4vec*)&Xcat[row * 4096 + col4 * 4]        = xs;
  *(s4vec*)&Xcat[row * 4096 + 1024 + col4 * 4] = cs;
  *(s4vec*)&XY[row * 3072 + col4 * 4]          = xs;
}

__global__ __launch_bounds__(256)
void cast_state(const float4* __restrict__ s, short* __restrict__ Xcat)
{
  const size_t i = (size_t)blockIdx.x * 256 + threadIdx.x;
  if (i >= (size_t)BB * (SS / 4)) return;
  const size_t row = i >> 9;           // SS/4 = 512
  const int col4 = (int)(i & 511);
  const float4 sv = s[i];
  const s4vec ss = { f2bf(sv.x), f2bf(sv.y), f2bf(sv.z), f2bf(sv.w) };
  *(s4vec*)&Xcat[row * 4096 + 2048 + col4 * 4] = ss;
}

// row-wise LayerNorm over D=1024: 256 threads/row, float4 per thread
__global__ __launch_bounds__(256)
void ln_kernel(const float* __restrict__ h, const float* __restrict__ w,
               const float* __restrict__ b, float* __restrict__ out)
{
  const int row = blockIdx.x;
  const int t = threadIdx.x;
  const float4 v = ((const float4*)(h + (size_t)row * DD))[t];
  float s  = v.x + v.y + v.z + v.w;
  float sq = v.x * v.x + v.y * v.y + v.z * v.z + v.w * v.w;
#pragma unroll
  for (int off = 32; off; off >>= 1) {
    s  += __shfl_down(s, off);
    sq += __shfl_down(sq, off);
  }
  __shared__ float ss[4], ssq[4];
  const int lane = t & 63, wv = t >> 6;
  if (lane == 0) { ss[wv] = s; ssq[wv] = sq; }
  __syncthreads();
  const float st  = ss[0] + ss[1] + ss[2] + ss[3];
  const float sqt = ssq[0] + ssq[1] + ssq[2] + ssq[3];
  const float mu  = st * (1.f / (float)DD);
  const float var = sqt * (1.f / (float)DD) - mu * mu;
  const float rstd = rsqrtf(var + 1e-5f);
  const float4 wv4 = ((const float4*)w)[t];
  const float4 bv4 = ((const float4*)b)[t];
  float4 o;
  o.x = (v.x - mu) * rstd * wv4.x + bv4.x;
  o.y = (v.y - mu) * rstd * wv4.y + bv4.y;
  o.z = (v.z - mu) * rstd * wv4.z + bv4.z;
  o.w = (v.w - mu) * rstd * wv4.w + bv4.w;
  ((float4*)(out + (size_t)row * DD))[t] = o;
}

extern "C" void kernel_launch(void* const* d_in, const int* in_sizes, int n_in,
                              void* d_out, int out_size, void* d_ws, size_t ws_size,
                              hipStream_t stream)
{
  const float* x_t    = (const float*)d_in[0];
  const float* state  = (const float*)d_in[1];
  const float* cond   = (const float*)d_in[2];
  const float* carry  = (const float*)d_in[3];
  const float* W_step = (const float*)d_in[4];
  const float* b_step = (const float*)d_in[5];
  const float* W_cstep= (const float*)d_in[6];
  const float* W_in   = (const float*)d_in[7];
  const float* b_in   = (const float*)d_in[8];
  const float* W_cin  = (const float*)d_in[9];
  const float* W_state= (const float*)d_in[10];
  const float* W_out  = (const float*)d_in[11];
  const float* b_out  = (const float*)d_in[12];
  const float* ln_w   = (const float*)d_in[13];
  const float* ln_b   = (const float*)d_in[14];
  const float* ldec   = (const float*)d_in[15];

  char* ws = (char*)d_ws;
  size_t off = 0;
  short* Xcat = (short*)(ws + off); off += (size_t)BB * 4096 * 2;   // 128 MB
  short* XY   = (short*)(ws + off); off += (size_t)BB * 3072 * 2;   //  96 MB
  float* A1   = (float*)(ws + off); off += (size_t)BB * SS * 4;     // 128 MB
  short* WstepT  = (short*)(ws + off); off += (size_t)SS * DD * 2;  //   4 MB
  short* WcstepT = (short*)(ws + off); off += (size_t)SS * DD * 2;  //   4 MB
  short* WcatT   = (short*)(ws + off); off += (size_t)SS * 4096 * 2;//  16 MB
  short* WoutT   = (short*)(ws + off); off += (size_t)DD * 3072 * 2;//   6 MB
  float* hbuf = A1;  // overlay: A1 dead after gemm<2>, h written by gemm<3>

  float* out_ln    = (float*)d_out;
  float* out_state = (float*)d_out + (size_t)BB * DD;

  // 1) activation casts
  cast_xc<<<dim3(BB * (DD / 4) / 256), 256, 0, stream>>>(
      (const float4*)x_t, (const float4*)cond, Xcat, XY);
  cast_state<<<dim3(BB * (SS / 4) / 256), 256, 0, stream>>>(
      (const float4*)state, Xcat);

  // 2) weight transpose-casts: W(K,N) fp32 -> Wt(N,K) bf16
  tcast<<<dim3(SS / 32, DD / 32), dim3(32, 8), 0, stream>>>(W_step, DD, SS, WstepT, DD, 0);
  tcast<<<dim3(SS / 32, DD / 32), dim3(32, 8), 0, stream>>>(W_cstep, DD, SS, WcstepT, DD, 0);
  tcast<<<dim3(SS / 32, DD / 32), dim3(32, 8), 0, stream>>>(W_in,   DD, SS, WcatT, 4096, 0);
  tcast<<<dim3(SS / 32, DD / 32), dim3(32, 8), 0, stream>>>(W_cin,  DD, SS, WcatT, 4096, 1024);
  tcast<<<dim3(SS / 32, SS / 32), dim3(32, 8), 0, stream>>>(W_state, SS, SS, WcatT, 4096, 2048);
  tcast<<<dim3(DD / 32, 3072 / 32), dim3(32, 8), 0, stream>>>(W_out, 3072, DD, WoutT, 3072, 0);

  const dim3 gS(SS / 128, BB / 128);  // (16,128) GEMMs 1-3
  const dim3 gD(DD / 128, BB / 128);  // (8,128)  GEMM 4

  // 3) A1 = softplus(x @ W_step + b_step)
  EpiParams p1{}; p1.out = A1; p1.bias = b_step;
  gemm_bt<0><<<gS, 256, 0, stream>>>(Xcat, 4096, WstepT, DD, DD, p1);

  // 4) A1 += 0.1*softplus(cond @ W_cstep)
  EpiParams p2{}; p2.out = A1;
  gemm_bt<1><<<gS, 256, 0, stream>>>(Xcat + 1024, 4096, WcstepT, DD, DD, p2);

  // 5) P = [x|cond|state] @ [W_in;W_cin;W_state]; fused state update epilogue
  EpiParams p3{};
  p3.bias = b_in; p3.step = A1; p3.state = state; p3.carry = carry;
  p3.ldec = ldec; p3.out_state = out_state; p3.xy = XY;
  gemm_bt<2><<<gS, 256, 0, stream>>>(Xcat, 4096, WcatT, 4096, 4096, p3);

  // 6) h = [x|new_state] @ W_out + b_out + x
  EpiParams p4{}; p4.out = hbuf; p4.bias = b_out; p4.x = x_t;
  gemm_bt<3><<<gD, 256, 0, stream>>>(XY, 3072, WoutT, 3072, 3072, p4);

  // 7) LayerNorm
  ln_kernel<<<dim3(BB), 256, 0, stream>>>(hbuf, ln_w, ln_b, out_ln);
}